// Round 5
// baseline (686.745 us; speedup 1.0000x reference)
//
#include <hip/hip_runtime.h>

// y[b,o] = sum_i x[b,i]*W[i,o]*w_mask[b,i,o] + bias[o]*b_mask[b,o]
// B=32, IN_F=1024, OUT_F=4096. f32 tensors, int32 masks.
//
// R2/R3/R4 post-mortem: kernel time ~165-195 us regardless of load width
// (dword vs int4) or occupancy (2 vs 4 blk/CU) => already BW-bound, but on
// ~1.05 GB of traffic, not 537 MB: weight slices were re-fetched from HBM
// by each of the 512 blocks (L2 dedup not happening; 537+512 MB @ 6.3 TB/s
// = 167 us, matching all rounds). Fix: WEIGHT-STATIONARY blocks — each
// thread keeps its 32xfloat4 weight column in registers (loaded once) and
// loops over 8 batch rows streaming only mask. Weight HBM <= 64 MiB by
// construction (16 MiB if XCD slice-colocation via bid=bgrp*128+s works).

#define B_DIM 32
#define IN_F 1024
#define OUT_F 4096
#define BO (B_DIM * OUT_F)     // 131072
#define I_CHUNK 32             // i-rows held in registers per block
#define N_CHUNK (IN_F / I_CHUNK)  // 32
#define B_PER 8                // batch rows per block
#define N_BGRP (B_DIM / B_PER) // 4

typedef int   v4i __attribute__((ext_vector_type(4)));
typedef float v4f __attribute__((ext_vector_type(4)));

// partial[chunk][b][o] : 32 x 32 x 4096 f32 = 16 MiB in d_ws
__global__ __launch_bounds__(256, 2) void masked_gemv_partial(
    const float* __restrict__ x,       // [B, IN_F]
    const float* __restrict__ weight,  // [IN_F, OUT_F]
    const int* __restrict__ w_mask,    // [B, IN_F, OUT_F]
    float* __restrict__ partial)
{
    // bid = bgrp*128 + (chunk*4 + o_blk): the 4 bgrp-sharers of a weight
    // slice differ by 128 (128%8==0 -> same XCD under round-robin).
    const int bid   = blockIdx.x;
    const int bgrp  = bid >> 7;
    const int s     = bid & 127;
    const int chunk = s >> 2;
    const int o_blk = s & 3;
    const int i0    = chunk * I_CHUNK;
    const int o     = o_blk * 1024 + (threadIdx.x << 2);

    // Stage x[bgrp*8 .. +8, i0 .. +32] in LDS (1 KiB), one element/thread.
    __shared__ float xs[B_PER][I_CHUNK];
    {
        const int bb = threadIdx.x >> 5, ii = threadIdx.x & 31;
        xs[bb][ii] = x[(bgrp * B_PER + bb) * IN_F + i0 + ii];
    }

    // Weight column tile -> registers, loaded once per block (coalesced).
    v4f wreg[I_CHUNK];
    const float* wptr = weight + (size_t)i0 * OUT_F + o;
#pragma unroll
    for (int i = 0; i < I_CHUNK; ++i)
        wreg[i] = *(const v4f*)(wptr + (size_t)i * OUT_F);

    __syncthreads();

    for (int bb = 0; bb < B_PER; ++bb) {
        const int b = bgrp * B_PER + bb;
        const int* mptr =
            w_mask + ((size_t)b * IN_F + i0) * OUT_F + o;
        v4f acc = {0.f, 0.f, 0.f, 0.f};
#pragma unroll
        for (int i = 0; i < I_CHUNK; ++i) {
            const v4i m = __builtin_nontemporal_load(
                (const v4i*)(mptr + (size_t)i * OUT_F));
            const float xi = xs[bb][i];  // wave-uniform -> LDS broadcast
            acc.x = fmaf(xi * (float)m.x, wreg[i].x, acc.x);
            acc.y = fmaf(xi * (float)m.y, wreg[i].y, acc.y);
            acc.z = fmaf(xi * (float)m.z, wreg[i].z, acc.z);
            acc.w = fmaf(xi * (float)m.w, wreg[i].w, acc.w);
        }
        __builtin_nontemporal_store(acc,
            (v4f*)(partial + ((size_t)chunk * B_DIM + b) * OUT_F + o));
    }
}

__global__ __launch_bounds__(256) void reduce_bias_kernel(
    const float* __restrict__ partial,  // [N_CHUNK][B][OUT_F]
    const float* __restrict__ bias,     // [OUT_F]
    const int* __restrict__ b_mask,     // [B, OUT_F]
    float* __restrict__ out)            // [B, OUT_F]
{
    const int tid = blockIdx.x * 256 + threadIdx.x;  // [0, BO)
    float s = 0.f;
#pragma unroll
    for (int c = 0; c < N_CHUNK; ++c)
        s += partial[(size_t)c * BO + tid];
    const int o = tid & (OUT_F - 1);
    out[tid] = fmaf(bias[o], (float)b_mask[tid], s);
}

extern "C" void kernel_launch(void* const* d_in, const int* in_sizes, int n_in,
                              void* d_out, int out_size, void* d_ws, size_t ws_size,
                              hipStream_t stream) {
    const float* x      = (const float*)d_in[0];
    const float* weight = (const float*)d_in[1];
    const float* bias   = (const float*)d_in[2];
    const int*   w_mask = (const int*)d_in[3];
    const int*   b_mask = (const int*)d_in[4];
    float* out     = (float*)d_out;
    float* partial = (float*)d_ws;  // 16 MiB used

    masked_gemv_partial<<<N_BGRP * 128, 256, 0, stream>>>(x, weight, w_mask, partial);
    reduce_bias_kernel<<<BO / 256, 256, 0, stream>>>(partial, bias, b_mask, out);
}